// Round 1
// baseline (281.573 us; speedup 1.0000x reference)
//
#include <hip/hip_runtime.h>

// LabelLoss: out[b] = sum_{n,c<7} (pred[b,n,c] - gt[b,n,c])^2
// pred/gt: [256, 16384, 8] fp32 contiguous. Memory-bound streaming reduction.
//
// Layout trick: 8 floats per object = 2 float4s. Even float4 (chan 0-3) keeps
// all 4 lanes; odd float4 (chan 4-7) drops .w (chan 7). With a stride-256
// loop, (i & 1) is constant per lane -> uniform mask, no divergence.

#define THREADS 256
#define SPLIT 8                          // blocks per batch row
#define F4_PER_BATCH (16384 * 2)         // 32768 float4s per batch per input
#define F4_PER_BLOCK (F4_PER_BATCH / SPLIT)  // 4096

__global__ __launch_bounds__(THREADS) void label_loss_kernel(
    const float4* __restrict__ pred,
    const float4* __restrict__ gt,
    float* __restrict__ out)
{
    const int bx  = blockIdx.x;
    const int b   = bx / SPLIT;
    const int seg = bx % SPLIT;
    const long base = (long)b * F4_PER_BATCH + (long)seg * F4_PER_BLOCK;

    float acc = 0.0f;
    // 16 iterations per thread; consecutive lanes hit consecutive float4s
    // (16 B/lane coalesced).
    for (int i = threadIdx.x; i < F4_PER_BLOCK; i += THREADS) {
        const long j = base + i;
        const float4 p = pred[j];
        const float4 g = gt[j];
        const float dx = p.x - g.x;
        const float dy = p.y - g.y;
        const float dz = p.z - g.z;
        const float dw = p.w - g.w;
        // odd float4 index -> channels 4..7 -> exclude channel 7 (.w)
        const float m = (i & 1) ? 0.0f : 1.0f;
        acc += dx * dx + dy * dy + dz * dz + m * (dw * dw);
    }

    // 64-lane wave reduction
    #pragma unroll
    for (int off = 32; off > 0; off >>= 1)
        acc += __shfl_down(acc, off, 64);

    __shared__ float wsum[THREADS / 64];
    const int lane = threadIdx.x & 63;
    const int wave = threadIdx.x >> 6;
    if (lane == 0) wsum[wave] = acc;
    __syncthreads();

    if (threadIdx.x == 0) {
        float v = wsum[0] + wsum[1] + wsum[2] + wsum[3];
        atomicAdd(&out[b], v);   // 8 partials per output element
    }
}

extern "C" void kernel_launch(void* const* d_in, const int* in_sizes, int n_in,
                              void* d_out, int out_size, void* d_ws, size_t ws_size,
                              hipStream_t stream) {
    const float4* pred = (const float4*)d_in[0];
    const float4* gt   = (const float4*)d_in[1];
    float* out = (float*)d_out;

    // d_out is re-poisoned to 0xAA before every launch; we accumulate with
    // atomics, so zero it first (async memset is graph-capture safe).
    hipMemsetAsync(d_out, 0, (size_t)out_size * sizeof(float), stream);

    const int n_blocks = 256 * SPLIT;  // one batch row split across 8 blocks
    label_loss_kernel<<<dim3(n_blocks), dim3(THREADS), 0, stream>>>(pred, gt, out);
}

// Round 2
// 278.043 us; speedup vs baseline: 1.0127x; 1.0127x over previous
//
#include <hip/hip_runtime.h>

// LabelLoss: out[b] = sum_{n,c<7} (pred[b,n,c] - gt[b,n,c])^2
// pred/gt: [256, 16384, 8] fp32 contiguous. Memory-latency-bound streaming
// reduction. R1 showed 12 VGPRs / 2.5 TB/s effective: only 2 loads in flight
// per wave. This version unrolls x4 -> 8 independent dwordx4 loads in flight
// (8 KB/wave MLP), 4 accumulators, still <=~48 VGPRs so full occupancy.

#define THREADS 256
#define SPLIT 8                               // blocks per batch row
#define F4_PER_BATCH (16384 * 2)              // 32768 float4s per batch per input
#define F4_PER_BLOCK (F4_PER_BATCH / SPLIT)   // 4096
#define UNROLL 4
#define OUTER (F4_PER_BLOCK / (THREADS * UNROLL))  // 4

__global__ __launch_bounds__(THREADS) void label_loss_kernel(
    const float4* __restrict__ pred,
    const float4* __restrict__ gt,
    float* __restrict__ out)
{
    const int bx  = blockIdx.x;
    const int b   = bx / SPLIT;
    const int seg = bx % SPLIT;
    const long base = (long)b * F4_PER_BATCH + (long)seg * F4_PER_BLOCK;

    // Channel-7 mask: element i covers channels 4..7 iff i is odd. All
    // unrolled offsets are multiples of 256 (even), so parity == tid&1:
    // lane-uniform, no divergence.
    const float m = (threadIdx.x & 1) ? 0.0f : 1.0f;

    float acc0 = 0.0f, acc1 = 0.0f, acc2 = 0.0f, acc3 = 0.0f;

    for (int it = 0; it < OUTER; ++it) {
        const long i0 = base + (long)it * (THREADS * UNROLL) + threadIdx.x;
        // 8 independent 16B loads issued back-to-back before any use.
        const float4 p0 = pred[i0];
        const float4 p1 = pred[i0 + 256];
        const float4 p2 = pred[i0 + 512];
        const float4 p3 = pred[i0 + 768];
        const float4 g0 = gt[i0];
        const float4 g1 = gt[i0 + 256];
        const float4 g2 = gt[i0 + 512];
        const float4 g3 = gt[i0 + 768];

        float dx, dy, dz, dw;
        dx = p0.x - g0.x; dy = p0.y - g0.y; dz = p0.z - g0.z; dw = p0.w - g0.w;
        acc0 += dx * dx + dy * dy + dz * dz + m * (dw * dw);
        dx = p1.x - g1.x; dy = p1.y - g1.y; dz = p1.z - g1.z; dw = p1.w - g1.w;
        acc1 += dx * dx + dy * dy + dz * dz + m * (dw * dw);
        dx = p2.x - g2.x; dy = p2.y - g2.y; dz = p2.z - g2.z; dw = p2.w - g2.w;
        acc2 += dx * dx + dy * dy + dz * dz + m * (dw * dw);
        dx = p3.x - g3.x; dy = p3.y - g3.y; dz = p3.z - g3.z; dw = p3.w - g3.w;
        acc3 += dx * dx + dy * dy + dz * dz + m * (dw * dw);
    }

    float acc = (acc0 + acc1) + (acc2 + acc3);

    // 64-lane wave reduction
    #pragma unroll
    for (int off = 32; off > 0; off >>= 1)
        acc += __shfl_down(acc, off, 64);

    __shared__ float wsum[THREADS / 64];
    const int lane = threadIdx.x & 63;
    const int wave = threadIdx.x >> 6;
    if (lane == 0) wsum[wave] = acc;
    __syncthreads();

    if (threadIdx.x == 0) {
        float v = wsum[0] + wsum[1] + wsum[2] + wsum[3];
        atomicAdd(&out[b], v);   // 8 partials per output element
    }
}

extern "C" void kernel_launch(void* const* d_in, const int* in_sizes, int n_in,
                              void* d_out, int out_size, void* d_ws, size_t ws_size,
                              hipStream_t stream) {
    const float4* pred = (const float4*)d_in[0];
    const float4* gt   = (const float4*)d_in[1];
    float* out = (float*)d_out;

    // d_out is re-poisoned to 0xAA before every launch; we accumulate with
    // atomics, so zero it first (async memset is graph-capture safe).
    hipMemsetAsync(d_out, 0, (size_t)out_size * sizeof(float), stream);

    const int n_blocks = 256 * SPLIT;  // one batch row split across 8 blocks
    label_loss_kernel<<<dim3(n_blocks), dim3(THREADS), 0, stream>>>(pred, gt, out);
}

// Round 3
// 271.933 us; speedup vs baseline: 1.0355x; 1.0225x over previous
//
#include <hip/hip_runtime.h>

// LabelLoss: out[b] = sum_{n,c<7} (pred[b,n,c] - gt[b,n,c])^2
// pred/gt: [256, 16384, 8] fp32. Streaming reduction, stuck at ~2.7 TB/s
// effective read BW (42% of achievable). R3: maximize per-wave MLP with a
// straight-line body -- 16 independent dwordx4 loads issued before any use,
// no loop-carried dependency -- and 2x grid oversubscription (4096 blocks)
// so block drain overlaps block start.

#define THREADS 256
#define SPLIT 16                              // blocks per batch row
#define F4_PER_BATCH (16384 * 2)              // 32768 float4s per batch per input
#define F4_PER_BLOCK (F4_PER_BATCH / SPLIT)   // 2048 = 256 threads * 8
#define UNROLL 8

__global__ __launch_bounds__(THREADS) void label_loss_kernel(
    const float4* __restrict__ pred,
    const float4* __restrict__ gt,
    float* __restrict__ out)
{
    const int bx  = blockIdx.x;
    const int b   = bx / SPLIT;
    const int seg = bx % SPLIT;
    const long i0 = (long)b * F4_PER_BATCH + (long)seg * F4_PER_BLOCK
                  + threadIdx.x;

    // Channel-7 mask: float4 index i covers channels 4..7 iff i is odd.
    // Unroll stride 256 is even -> parity == tid&1: lane-uniform, no
    // divergence.
    const float m = (threadIdx.x & 1) ? 0.0f : 1.0f;

    // Issue all 16 loads before any consumption.
    float4 p[UNROLL], g[UNROLL];
    #pragma unroll
    for (int k = 0; k < UNROLL; ++k) p[k] = pred[i0 + k * THREADS];
    #pragma unroll
    for (int k = 0; k < UNROLL; ++k) g[k] = gt[i0 + k * THREADS];

    float acc[UNROLL];
    #pragma unroll
    for (int k = 0; k < UNROLL; ++k) {
        const float dx = p[k].x - g[k].x;
        const float dy = p[k].y - g[k].y;
        const float dz = p[k].z - g[k].z;
        const float dw = p[k].w - g[k].w;
        acc[k] = dx * dx + dy * dy + dz * dz + m * (dw * dw);
    }

    float v = ((acc[0] + acc[1]) + (acc[2] + acc[3]))
            + ((acc[4] + acc[5]) + (acc[6] + acc[7]));

    // 64-lane wave reduction
    #pragma unroll
    for (int off = 32; off > 0; off >>= 1)
        v += __shfl_down(v, off, 64);

    __shared__ float wsum[THREADS / 64];
    const int lane = threadIdx.x & 63;
    const int wave = threadIdx.x >> 6;
    if (lane == 0) wsum[wave] = v;
    __syncthreads();

    if (threadIdx.x == 0) {
        atomicAdd(&out[b], wsum[0] + wsum[1] + wsum[2] + wsum[3]);
    }
}

extern "C" void kernel_launch(void* const* d_in, const int* in_sizes, int n_in,
                              void* d_out, int out_size, void* d_ws, size_t ws_size,
                              hipStream_t stream) {
    const float4* pred = (const float4*)d_in[0];
    const float4* gt   = (const float4*)d_in[1];
    float* out = (float*)d_out;

    // d_out is re-poisoned to 0xAA before every launch; we accumulate with
    // atomics, so zero it first (async memset is graph-capture safe).
    hipMemsetAsync(d_out, 0, (size_t)out_size * sizeof(float), stream);

    const int n_blocks = 256 * SPLIT;  // 4096 blocks, 16 queued per CU
    label_loss_kernel<<<dim3(n_blocks), dim3(THREADS), 0, stream>>>(pred, gt, out);
}